// Round 1
// baseline (409.220 us; speedup 1.0000x reference)
//
#include <hip/hip_runtime.h>
#include <hip/hip_bf16.h>
#include <cstdint>

typedef __bf16 bf16_t;
typedef __bf16 bf16x8 __attribute__((ext_vector_type(8)));
typedef __bf16 bf16x4 __attribute__((ext_vector_type(4)));
typedef float f32x4 __attribute__((ext_vector_type(4)));

#define SEQ    1024
#define BATCH  8
#define NTOK   8192      // BATCH*SEQ
#define DMODEL 1024
#define NHEAD  16
#define HD     64
#define FFDIM  2048

// ---------------------------------------------------------------------------
// async global->LDS, 16B per lane. LDS base must be wave-uniform; HW writes
// base + lane*16. Global address is per-lane.
__device__ __forceinline__ void async16(const void* g, void* l) {
  __builtin_amdgcn_global_load_lds(
      (const __attribute__((address_space(1))) void*)g,
      (__attribute__((address_space(3))) void*)l, 16, 0, 0);
}

// ---------------------------------------------------------------------------
// elementwise fp32 -> bf16 cast (vectorized)
__global__ __launch_bounds__(256)
void cast_bf16_kernel(const float* __restrict__ in, bf16_t* __restrict__ out, int n4) {
  int i = blockIdx.x * 256 + threadIdx.x;
  if (i >= n4) return;
  float4 v = ((const float4*)in)[i];
  bf16x4 o = { (bf16_t)v.x, (bf16_t)v.y, (bf16_t)v.z, (bf16_t)v.w };
  *(bf16x4*)&out[(size_t)i * 4] = o;
}

// ---------------------------------------------------------------------------
// transpose + cast: W fp32 [R][C] row-major -> Wt bf16 [C][R] row-major
__global__ __launch_bounds__(256)
void transpose_cast_kernel(const float* __restrict__ W, bf16_t* __restrict__ Wt,
                           int R, int C) {
  __shared__ float tile[32][33];
  const int bx = blockIdx.x * 32;  // col base in W
  const int by = blockIdx.y * 32;  // row base in W
  const int tx = threadIdx.x;      // 0..31
  const int ty = threadIdx.y;      // 0..7
#pragma unroll
  for (int i = 0; i < 4; ++i)
    tile[ty + 8 * i][tx] = W[(size_t)(by + ty + 8 * i) * C + bx + tx];
  __syncthreads();
#pragma unroll
  for (int i = 0; i < 4; ++i)
    Wt[(size_t)(bx + ty + 8 * i) * R + by + tx] = (bf16_t)tile[tx][ty + 8 * i];
}

// ---------------------------------------------------------------------------
// GEMM: C[M,N] = A[M,K] * Bt[N,K]^T + bias, bf16 inputs, fp32 accumulate.
// 128x128 tile, BK=64, 256 threads = 4 waves (2x2), each wave 64x64 (4x4 frags
// of 16x16x32). Single-buffered LDS, global_load_lds staging.
// EPI: 0 = fp32 row-major out
//      1 = bf16 relu row-major out
//      2 = bf16 out permuted to [b,h,s,e]   (Q/K buffers)
//      3 = bf16 out permuted to [b,h,e,s]   (V^T buffer)
template <int EPI>
__global__ __launch_bounds__(256)
void gemm_bt(const bf16_t* __restrict__ A, const bf16_t* __restrict__ Bt,
             const float* __restrict__ bias, void* __restrict__ outp,
             int M, int N, int K) {
  __shared__ bf16_t As[128 * 64];
  __shared__ bf16_t Bs[128 * 64];
  const int tid = threadIdx.x;
  const int wave = tid >> 6, lane = tid & 63;
  const int wr = (wave >> 1) * 64, wc = (wave & 1) * 64;
  const int bm = blockIdx.x * 128, bn = blockIdx.y * 128;

  f32x4 acc[4][4];
#pragma unroll
  for (int i = 0; i < 4; ++i)
#pragma unroll
    for (int j = 0; j < 4; ++j) acc[i][j] = (f32x4){0.f, 0.f, 0.f, 0.f};

  const int lcol = (lane & 7) * 8;   // k-offset within 64 for staging
  const int fr = lane & 15, kg = (lane >> 4) * 8;

  const int nk = K >> 6;
  for (int kt = 0; kt < nk; ++kt) {
    const int k0 = kt << 6;
#pragma unroll
    for (int i = 0; i < 4; ++i) {
      const int chunk = i * 4 + wave;              // 0..15, 8 rows each
      const int row = chunk * 8 + (lane >> 3);
      async16(&A[(size_t)(bm + row) * K + k0 + lcol], &As[chunk * 512]);
      async16(&Bt[(size_t)(bn + row) * K + k0 + lcol], &Bs[chunk * 512]);
    }
    asm volatile("s_waitcnt vmcnt(0)" ::: "memory");
    __syncthreads();

#pragma unroll
    for (int kk = 0; kk < 2; ++kk) {
      bf16x8 a[4], b[4];
      const int ko = kk * 32 + kg;
#pragma unroll
      for (int i = 0; i < 4; ++i) a[i] = *(const bf16x8*)&As[(wr + i * 16 + fr) * 64 + ko];
#pragma unroll
      for (int j = 0; j < 4; ++j) b[j] = *(const bf16x8*)&Bs[(wc + j * 16 + fr) * 64 + ko];
#pragma unroll
      for (int i = 0; i < 4; ++i)
#pragma unroll
        for (int j = 0; j < 4; ++j)
          acc[i][j] = __builtin_amdgcn_mfma_f32_16x16x32_bf16(a[i], b[j], acc[i][j], 0, 0, 0);
    }
    __syncthreads();
  }

  const int lr = (lane >> 4) * 4, lc = lane & 15;
#pragma unroll
  for (int j = 0; j < 4; ++j) {
    const int col = bn + wc + j * 16 + lc;
    const float bv = bias[col];
#pragma unroll
    for (int i = 0; i < 4; ++i) {
#pragma unroll
      for (int r = 0; r < 4; ++r) {
        const int row = bm + wr + i * 16 + lr + r;
        const float v = acc[i][j][r] + bv;
        if (EPI == 0) {
          ((float*)outp)[(size_t)row * N + col] = v;
        } else if (EPI == 1) {
          ((bf16_t*)outp)[(size_t)row * N + col] = (bf16_t)fmaxf(v, 0.f);
        } else if (EPI == 2) {
          const int b_ = row >> 10, s_ = row & 1023, h_ = col >> 6, e_ = col & 63;
          ((bf16_t*)outp)[((size_t)((b_ * NHEAD + h_) * SEQ + s_)) * HD + e_] = (bf16_t)v;
        } else {
          const int b_ = row >> 10, s_ = row & 1023, h_ = col >> 6, e_ = col & 63;
          ((bf16_t*)outp)[((size_t)((b_ * NHEAD + h_) * HD + e_)) * SEQ + s_] = (bf16_t)v;
        }
      }
    }
  }
}

// ---------------------------------------------------------------------------
// Flash attention: per (b,h) and 128-row Q tile. KV tiles of 64.
// Q/K: [b,h,s,64] bf16;  VT: [b,h,64,s] bf16;  CTX out: [token, h*64+c] bf16.
__global__ __launch_bounds__(256)
void attn_kernel(const bf16_t* __restrict__ Q, const bf16_t* __restrict__ K,
                 const bf16_t* __restrict__ VT, bf16_t* __restrict__ CTX) {
  const int bh = blockIdx.x;        // 0..127
  const int qt = blockIdx.y * 128;  // q row base
  const int b_ = bh >> 4, h_ = bh & 15;
  const bf16_t* qh = Q + (size_t)bh * SEQ * HD;
  const bf16_t* kh = K + (size_t)bh * SEQ * HD;
  const bf16_t* vh = VT + (size_t)bh * HD * SEQ;
  const int tid = threadIdx.x, wave = tid >> 6, lane = tid & 63;
  const int fr = lane & 15, kg = (lane >> 4) * 8;
  const int lr = (lane >> 4) * 4, lc = lane & 15;

  __shared__ bf16_t Ks[64 * 64];
  __shared__ bf16_t Vs[64 * 64];
  __shared__ bf16_t Ps[128 * 64];

  // Q fragments in registers (wave owns q rows [wave*32, wave*32+32))
  bf16x8 qf[2][2];
#pragma unroll
  for (int i = 0; i < 2; ++i)
#pragma unroll
    for (int kk = 0; kk < 2; ++kk)
      qf[i][kk] = *(const bf16x8*)&qh[(size_t)(qt + wave * 32 + i * 16 + fr) * HD + kk * 32 + kg];

  f32x4 octx[2][4];
  float mrun[2][4], lrun[2][4];
#pragma unroll
  for (int i = 0; i < 2; ++i)
#pragma unroll
    for (int j = 0; j < 4; ++j) octx[i][j] = (f32x4){0.f, 0.f, 0.f, 0.f};
#pragma unroll
  for (int i = 0; i < 2; ++i)
#pragma unroll
    for (int r = 0; r < 4; ++r) { mrun[i][r] = -1e30f; lrun[i][r] = 0.f; }

  for (int t = 0; t < SEQ / 64; ++t) {
    __syncthreads();  // all waves done with previous K/V/P reads
#pragma unroll
    for (int i = 0; i < 2; ++i) {
      const int chunk = i * 4 + wave;            // 0..7
      const int row = chunk * 8 + (lane >> 3);   // 0..63
      const int col = (lane & 7) * 8;
      async16(&kh[(size_t)(t * 64 + row) * HD + col], &Ks[chunk * 512]);
      async16(&vh[(size_t)row * SEQ + t * 64 + col], &Vs[chunk * 512]);
    }
    asm volatile("s_waitcnt vmcnt(0)" ::: "memory");
    __syncthreads();

    // S = q @ k^T   (wave: 32 q rows x 64 kv cols)
    f32x4 sc[2][4];
#pragma unroll
    for (int i = 0; i < 2; ++i)
#pragma unroll
      for (int j = 0; j < 4; ++j) sc[i][j] = (f32x4){0.f, 0.f, 0.f, 0.f};
#pragma unroll
    for (int kk = 0; kk < 2; ++kk) {
      bf16x8 kf[4];
#pragma unroll
      for (int j = 0; j < 4; ++j) kf[j] = *(const bf16x8*)&Ks[(j * 16 + fr) * 64 + kk * 32 + kg];
#pragma unroll
      for (int i = 0; i < 2; ++i)
#pragma unroll
        for (int j = 0; j < 4; ++j)
          sc[i][j] = __builtin_amdgcn_mfma_f32_16x16x32_bf16(qf[i][kk], kf[j], sc[i][j], 0, 0, 0);
    }
#pragma unroll
    for (int i = 0; i < 2; ++i)
#pragma unroll
      for (int j = 0; j < 4; ++j)
#pragma unroll
        for (int r = 0; r < 4; ++r) sc[i][j][r] *= 0.125f;

    // online softmax per q-row; rows live on (lane>>4) groups, cols on lane&15
#pragma unroll
    for (int i = 0; i < 2; ++i) {
#pragma unroll
      for (int r = 0; r < 4; ++r) {
        float mx = fmaxf(fmaxf(sc[i][0][r], sc[i][1][r]), fmaxf(sc[i][2][r], sc[i][3][r]));
#pragma unroll
        for (int m = 1; m < 16; m <<= 1) mx = fmaxf(mx, __shfl_xor(mx, m));
        const float mnew = fmaxf(mrun[i][r], mx);
        const float alpha = __expf(mrun[i][r] - mnew);
        float rs = 0.f;
#pragma unroll
        for (int j = 0; j < 4; ++j) {
          const float p = __expf(sc[i][j][r] - mnew);
          sc[i][j][r] = p;
          rs += p;
        }
#pragma unroll
        for (int m = 1; m < 16; m <<= 1) rs += __shfl_xor(rs, m);
        lrun[i][r] = lrun[i][r] * alpha + rs;
        mrun[i][r] = mnew;
#pragma unroll
        for (int j = 0; j < 4; ++j) octx[i][j][r] *= alpha;
        const int prow = wave * 32 + i * 16 + lr + r;
#pragma unroll
        for (int j = 0; j < 4; ++j) Ps[prow * 64 + j * 16 + lc] = (bf16_t)sc[i][j][r];
      }
    }
    asm volatile("s_waitcnt lgkmcnt(0)" ::: "memory");  // P writes visible to own reads

    // ctx += P @ V   (Bt form: Vs[c][kv])
#pragma unroll
    for (int kk = 0; kk < 2; ++kk) {
      bf16x8 pf[2], vf[4];
#pragma unroll
      for (int i = 0; i < 2; ++i) pf[i] = *(const bf16x8*)&Ps[(wave * 32 + i * 16 + fr) * 64 + kk * 32 + kg];
#pragma unroll
      for (int j = 0; j < 4; ++j) vf[j] = *(const bf16x8*)&Vs[(j * 16 + fr) * 64 + kk * 32 + kg];
#pragma unroll
      for (int i = 0; i < 2; ++i)
#pragma unroll
        for (int j = 0; j < 4; ++j)
          octx[i][j] = __builtin_amdgcn_mfma_f32_16x16x32_bf16(pf[i], vf[j], octx[i][j], 0, 0, 0);
    }
  }

  // normalize and write ctx in [token, h*64+c] layout
#pragma unroll
  for (int i = 0; i < 2; ++i)
#pragma unroll
    for (int r = 0; r < 4; ++r) {
      const float inv = 1.f / lrun[i][r];
      const int row = qt + wave * 32 + i * 16 + lr + r;
#pragma unroll
      for (int j = 0; j < 4; ++j) {
        const int c = j * 16 + lc;
        CTX[((size_t)(b_ * SEQ + row)) * DMODEL + h_ * HD + c] = (bf16_t)(octx[i][j][r] * inv);
      }
    }
}

// ---------------------------------------------------------------------------
// residual + LayerNorm: out = LN(X+Y)*g + b ; optional bf16 copy
__global__ __launch_bounds__(256)
void ln_kernel(const float* __restrict__ X, const float* __restrict__ Y,
               const float* __restrict__ g, const float* __restrict__ b,
               float* __restrict__ outf, bf16_t* __restrict__ outb) {
  const int row = blockIdx.x, tid = threadIdx.x;
  const int wave = tid >> 6, lane = tid & 63;
  const float4 xv = ((const float4*)X)[(size_t)row * 256 + tid];
  const float4 yv = ((const float4*)Y)[(size_t)row * 256 + tid];
  const float s0 = xv.x + yv.x, s1 = xv.y + yv.y, s2 = xv.z + yv.z, s3 = xv.w + yv.w;
  float sum = s0 + s1 + s2 + s3;
  float sq = s0 * s0 + s1 * s1 + s2 * s2 + s3 * s3;
#pragma unroll
  for (int off = 1; off < 64; off <<= 1) {
    sum += __shfl_xor(sum, off);
    sq += __shfl_xor(sq, off);
  }
  __shared__ float red[8];
  if (lane == 0) { red[wave] = sum; red[4 + wave] = sq; }
  __syncthreads();
  sum = red[0] + red[1] + red[2] + red[3];
  sq = red[4] + red[5] + red[6] + red[7];
  const float mu = sum * (1.f / 1024.f);
  const float var = sq * (1.f / 1024.f) - mu * mu;
  const float rstd = rsqrtf(var + 1e-5f);
  const float4 gv = ((const float4*)g)[tid];
  const float4 bv = ((const float4*)b)[tid];
  const float o0 = (s0 - mu) * rstd * gv.x + bv.x;
  const float o1 = (s1 - mu) * rstd * gv.y + bv.y;
  const float o2 = (s2 - mu) * rstd * gv.z + bv.z;
  const float o3 = (s3 - mu) * rstd * gv.w + bv.w;
  ((float4*)outf)[(size_t)row * 256 + tid] = make_float4(o0, o1, o2, o3);
  if (outb) {
    bf16x4 ob = { (bf16_t)o0, (bf16_t)o1, (bf16_t)o2, (bf16_t)o3 };
    *(bf16x4*)&outb[(size_t)row * 1024 + tid * 4] = ob;
  }
}

// ---------------------------------------------------------------------------
extern "C" void kernel_launch(void* const* d_in, const int* in_sizes, int n_in,
                              void* d_out, int out_size, void* d_ws, size_t ws_size,
                              hipStream_t stream) {
  const float* x   = (const float*)d_in[0];
  const float* Wq  = (const float*)d_in[1];
  const float* bq  = (const float*)d_in[2];
  const float* Wk  = (const float*)d_in[3];
  const float* bk  = (const float*)d_in[4];
  const float* Wv  = (const float*)d_in[5];
  const float* bv  = (const float*)d_in[6];
  const float* Wo  = (const float*)d_in[7];
  const float* bo  = (const float*)d_in[8];
  const float* g1  = (const float*)d_in[9];
  const float* be1 = (const float*)d_in[10];
  const float* W1  = (const float*)d_in[11];
  const float* b1  = (const float*)d_in[12];
  const float* W2  = (const float*)d_in[13];
  const float* b2  = (const float*)d_in[14];
  const float* g2  = (const float*)d_in[15];
  const float* be2 = (const float*)d_in[16];

  char* ws = (char*)d_ws;
  size_t off = 0;
  auto alloc = [&](size_t bytes) {
    char* p = ws + off;
    off += (bytes + 255) & ~(size_t)255;
    return p;
  };
  const size_t MB = 1u << 20;
  bf16_t* xb  = (bf16_t*)alloc(16 * MB);  // x bf16; reused as CTX after QKV
  bf16_t* WqT = (bf16_t*)alloc(2 * MB);
  bf16_t* WkT = (bf16_t*)alloc(2 * MB);
  bf16_t* WvT = (bf16_t*)alloc(2 * MB);
  bf16_t* WoT = (bf16_t*)alloc(2 * MB);
  bf16_t* W1T = (bf16_t*)alloc(4 * MB);
  bf16_t* W2T = (bf16_t*)alloc(4 * MB);
  bf16_t* qb  = (bf16_t*)alloc(16 * MB);  // reused as hb after attention
  bf16_t* kb  = (bf16_t*)alloc(16 * MB);  // kb+vT reused as u (ffn1 out)
  bf16_t* vT  = (bf16_t*)alloc(16 * MB);
  float*  attnf = (float*)alloc(32 * MB); // reused as y (ffn2 out)
  float*  h     = (float*)alloc(32 * MB);
  bf16_t* ctx = xb;
  bf16_t* hb  = qb;
  bf16_t* u   = kb;
  float*  y   = attnf;

  // prep: casts + transposes
  cast_bf16_kernel<<<dim3(NTOK * DMODEL / 4 / 256), dim3(256), 0, stream>>>(x, xb, NTOK * DMODEL / 4);
  transpose_cast_kernel<<<dim3(32, 32), dim3(32, 8), 0, stream>>>(Wq, WqT, 1024, 1024);
  transpose_cast_kernel<<<dim3(32, 32), dim3(32, 8), 0, stream>>>(Wk, WkT, 1024, 1024);
  transpose_cast_kernel<<<dim3(32, 32), dim3(32, 8), 0, stream>>>(Wv, WvT, 1024, 1024);
  transpose_cast_kernel<<<dim3(32, 32), dim3(32, 8), 0, stream>>>(Wo, WoT, 1024, 1024);
  transpose_cast_kernel<<<dim3(64, 32), dim3(32, 8), 0, stream>>>(W1, W1T, 1024, 2048);
  transpose_cast_kernel<<<dim3(32, 64), dim3(32, 8), 0, stream>>>(W2, W2T, 2048, 1024);

  // QKV projections
  gemm_bt<2><<<dim3(64, 8), dim3(256), 0, stream>>>(xb, WqT, bq, qb, NTOK, DMODEL, DMODEL);
  gemm_bt<2><<<dim3(64, 8), dim3(256), 0, stream>>>(xb, WkT, bk, kb, NTOK, DMODEL, DMODEL);
  gemm_bt<3><<<dim3(64, 8), dim3(256), 0, stream>>>(xb, WvT, bv, vT, NTOK, DMODEL, DMODEL);

  // attention (writes ctx == xb; xb no longer needed)
  attn_kernel<<<dim3(128, 8), dim3(256), 0, stream>>>(qb, kb, vT, ctx);

  // output projection + residual + LN1
  gemm_bt<0><<<dim3(64, 8), dim3(256), 0, stream>>>(ctx, WoT, bo, attnf, NTOK, DMODEL, DMODEL);
  ln_kernel<<<dim3(NTOK), dim3(256), 0, stream>>>(x, attnf, g1, be1, h, hb);

  // FFN
  gemm_bt<1><<<dim3(64, 16), dim3(256), 0, stream>>>(hb, W1T, b1, u, NTOK, FFDIM, DMODEL);
  gemm_bt<0><<<dim3(64, 8), dim3(256), 0, stream>>>(u, W2T, b2, y, NTOK, DMODEL, FFDIM);
  ln_kernel<<<dim3(NTOK), dim3(256), 0, stream>>>(h, y, g2, be2, (float*)d_out, nullptr);
}

// Round 2
// 370.638 us; speedup vs baseline: 1.1041x; 1.1041x over previous
//
#include <hip/hip_runtime.h>
#include <hip/hip_bf16.h>
#include <cstdint>

typedef __bf16 bf16_t;
typedef __bf16 bf16x8 __attribute__((ext_vector_type(8)));
typedef __bf16 bf16x4 __attribute__((ext_vector_type(4)));
typedef float f32x4 __attribute__((ext_vector_type(4)));

#define SEQ    1024
#define BATCH  8
#define NTOK   8192      // BATCH*SEQ
#define DMODEL 1024
#define NHEAD  16
#define HD     64
#define FFDIM  2048

// ---------------------------------------------------------------------------
// async global->LDS, 16B per lane. LDS base must be wave-uniform; HW writes
// base + lane*16. Global address is per-lane.
__device__ __forceinline__ void async16(const void* g, void* l) {
  __builtin_amdgcn_global_load_lds(
      (const __attribute__((address_space(1))) void*)g,
      (__attribute__((address_space(3))) void*)l, 16, 0, 0);
}

// ---------------------------------------------------------------------------
// elementwise fp32 -> bf16 cast (vectorized)
__global__ __launch_bounds__(256)
void cast_bf16_kernel(const float* __restrict__ in, bf16_t* __restrict__ out, int n4) {
  int i = blockIdx.x * 256 + threadIdx.x;
  if (i >= n4) return;
  float4 v = ((const float4*)in)[i];
  bf16x4 o = { (bf16_t)v.x, (bf16_t)v.y, (bf16_t)v.z, (bf16_t)v.w };
  *(bf16x4*)&out[(size_t)i * 4] = o;
}

// ---------------------------------------------------------------------------
// transpose + cast: W fp32 [R][C] row-major -> Wt bf16 [C][R] row-major
__global__ __launch_bounds__(256)
void transpose_cast_kernel(const float* __restrict__ W, bf16_t* __restrict__ Wt,
                           int R, int C) {
  __shared__ float tile[32][33];
  const int bx = blockIdx.x * 32;  // col base in W
  const int by = blockIdx.y * 32;  // row base in W
  const int tx = threadIdx.x;      // 0..31
  const int ty = threadIdx.y;      // 0..7
#pragma unroll
  for (int i = 0; i < 4; ++i)
    tile[ty + 8 * i][tx] = W[(size_t)(by + ty + 8 * i) * C + bx + tx];
  __syncthreads();
#pragma unroll
  for (int i = 0; i < 4; ++i)
    Wt[(size_t)(bx + ty + 8 * i) * R + by + tx] = (bf16_t)tile[tx][ty + 8 * i];
}

// ---------------------------------------------------------------------------
// GEMM: C[M,N] = (A[M,K] * Bt[N,K]^T + bias) * scale, bf16 in, fp32 acc.
// 128x128 tile, BK=64, 256 threads = 4 waves (2x2), each wave 64x64 (4x4 frags
// of 16x16x32). Single-buffered LDS, global_load_lds staging.
// EPI: 0 = fp32 row-major out
//      1 = bf16 relu row-major out
//      2 = bf16 out permuted to [b,h,s,e]   (Q/K buffers)
//      3 = bf16 out permuted to [b,h,e,s]   (V^T buffer)
template <int EPI>
__global__ __launch_bounds__(256)
void gemm_bt(const bf16_t* __restrict__ A, const bf16_t* __restrict__ Bt,
             const float* __restrict__ bias, void* __restrict__ outp,
             int M, int N, int K, float scale) {
  __shared__ bf16_t As[128 * 64];
  __shared__ bf16_t Bs[128 * 64];
  const int tid = threadIdx.x;
  const int wave = tid >> 6, lane = tid & 63;
  const int wr = (wave >> 1) * 64, wc = (wave & 1) * 64;
  const int bm = blockIdx.x * 128, bn = blockIdx.y * 128;

  f32x4 acc[4][4];
#pragma unroll
  for (int i = 0; i < 4; ++i)
#pragma unroll
    for (int j = 0; j < 4; ++j) acc[i][j] = (f32x4){0.f, 0.f, 0.f, 0.f};

  const int lcol = (lane & 7) * 8;   // k-offset within 64 for staging
  const int fr = lane & 15, kg = (lane >> 4) * 8;

  const int nk = K >> 6;
  for (int kt = 0; kt < nk; ++kt) {
    const int k0 = kt << 6;
#pragma unroll
    for (int i = 0; i < 4; ++i) {
      const int chunk = i * 4 + wave;              // 0..15, 8 rows each
      const int row = chunk * 8 + (lane >> 3);
      async16(&A[(size_t)(bm + row) * K + k0 + lcol], &As[chunk * 512]);
      async16(&Bt[(size_t)(bn + row) * K + k0 + lcol], &Bs[chunk * 512]);
    }
    asm volatile("s_waitcnt vmcnt(0)" ::: "memory");
    __syncthreads();

#pragma unroll
    for (int kk = 0; kk < 2; ++kk) {
      bf16x8 a[4], b[4];
      const int ko = kk * 32 + kg;
#pragma unroll
      for (int i = 0; i < 4; ++i) a[i] = *(const bf16x8*)&As[(wr + i * 16 + fr) * 64 + ko];
#pragma unroll
      for (int j = 0; j < 4; ++j) b[j] = *(const bf16x8*)&Bs[(wc + j * 16 + fr) * 64 + ko];
#pragma unroll
      for (int i = 0; i < 4; ++i)
#pragma unroll
        for (int j = 0; j < 4; ++j)
          acc[i][j] = __builtin_amdgcn_mfma_f32_16x16x32_bf16(a[i], b[j], acc[i][j], 0, 0, 0);
    }
    __syncthreads();
  }

  const int lr = (lane >> 4) * 4, lc = lane & 15;
#pragma unroll
  for (int j = 0; j < 4; ++j) {
    const int col = bn + wc + j * 16 + lc;
    const float bv = bias[col];
#pragma unroll
    for (int i = 0; i < 4; ++i) {
#pragma unroll
      for (int r = 0; r < 4; ++r) {
        const int row = bm + wr + i * 16 + lr + r;
        const float v = (acc[i][j][r] + bv) * scale;
        if (EPI == 0) {
          ((float*)outp)[(size_t)row * N + col] = v;
        } else if (EPI == 1) {
          ((bf16_t*)outp)[(size_t)row * N + col] = (bf16_t)fmaxf(v, 0.f);
        } else if (EPI == 2) {
          const int b_ = row >> 10, s_ = row & 1023, h_ = col >> 6, e_ = col & 63;
          ((bf16_t*)outp)[((size_t)((b_ * NHEAD + h_) * SEQ + s_)) * HD + e_] = (bf16_t)v;
        } else {
          const int b_ = row >> 10, s_ = row & 1023, h_ = col >> 6, e_ = col & 63;
          ((bf16_t*)outp)[((size_t)((b_ * NHEAD + h_) * HD + e_)) * SEQ + s_] = (bf16_t)v;
        }
      }
    }
  }
}

// ---------------------------------------------------------------------------
// Flash attention v2: per (b,h) and 128-row Q tile. KV tiles of 64.
//  - K/V/P LDS tiles XOR-swizzled (chunk ^= row&7) to kill 16-way conflicts.
//    Staging keeps LDS dest linear and pre-swizzles the GLOBAL source column.
//  - Double-buffered K/V: stage(t+1) issued before compute(t); 1 barrier/tile.
//  - Softmax in exp2 domain (Q pre-scaled by 0.125*log2e in GEMM epilogue).
//  - Defer-max: skip max-reduce + rescale when tile max within +8 of running
//    max (wave-uniform __all). Row-sum kept as per-lane partial; reduced once
//    in the epilogue. Fast path has ZERO shuffles.
// Q/K: [b,h,s,64] bf16;  VT: [b,h,64,s] bf16;  CTX out: [token, h*64+c] bf16.
__global__ __launch_bounds__(256)
void attn_kernel(const bf16_t* __restrict__ Q, const bf16_t* __restrict__ K,
                 const bf16_t* __restrict__ VT, bf16_t* __restrict__ CTX) {
  const int bh = blockIdx.x;        // 0..127
  const int qt = blockIdx.y * 128;  // q row base
  const int b_ = bh >> 4, h_ = bh & 15;
  const bf16_t* qh = Q + (size_t)bh * SEQ * HD;
  const bf16_t* kh = K + (size_t)bh * SEQ * HD;
  const bf16_t* vh = VT + (size_t)bh * HD * SEQ;
  const int tid = threadIdx.x, wave = tid >> 6, lane = tid & 63;
  const int fr = lane & 15, kg = (lane >> 4) * 8;
  const int lr = (lane >> 4) * 4, lc = lane & 15;

  __shared__ bf16_t Ks[2][64 * 64];
  __shared__ bf16_t Vs[2][64 * 64];
  __shared__ bf16_t Ps[128 * 64];

  // staging geometry: lane writes LDS row srow (within 8-row chunk), chunk
  // slot lane&7; source column pre-swizzled so LDS holds swizzled layout.
  const int srow = lane >> 3;                    // 0..7
  const int scol = ((lane & 7) ^ srow) * 8;      // pre-swizzled global col

  // Q fragments in registers (wave owns q rows [wave*32, wave*32+32))
  bf16x8 qf[2][2];
#pragma unroll
  for (int i = 0; i < 2; ++i)
#pragma unroll
    for (int kk = 0; kk < 2; ++kk)
      qf[i][kk] = *(const bf16x8*)&qh[(size_t)(qt + wave * 32 + i * 16 + fr) * HD + kk * 32 + kg];

  f32x4 octx[2][4];
  float mrun[2][4], lrun[2][4];
#pragma unroll
  for (int i = 0; i < 2; ++i)
#pragma unroll
    for (int j = 0; j < 4; ++j) octx[i][j] = (f32x4){0.f, 0.f, 0.f, 0.f};
#pragma unroll
  for (int i = 0; i < 2; ++i)
#pragma unroll
    for (int r = 0; r < 4; ++r) { mrun[i][r] = -1e30f; lrun[i][r] = 0.f; }

  auto stage = [&](int buf, int t) {
#pragma unroll
    for (int i = 0; i < 2; ++i) {
      const int ch = i * 4 + wave;           // 0..7
      const int row = ch * 8 + srow;         // 0..63
      async16(&kh[(size_t)(t * 64 + row) * HD + scol], &Ks[buf][ch * 512]);
      async16(&vh[(size_t)row * SEQ + t * 64 + scol], &Vs[buf][ch * 512]);
    }
  };

  stage(0, 0);
  asm volatile("s_waitcnt vmcnt(0)" ::: "memory");
  __syncthreads();

  for (int t = 0; t < SEQ / 64; ++t) {
    const int cur = t & 1;
    if (t + 1 < SEQ / 64) stage(cur ^ 1, t + 1);

    // S = q @ k^T   (wave: 32 q rows x 64 kv cols), exp2-domain scores
    f32x4 sc[2][4];
#pragma unroll
    for (int i = 0; i < 2; ++i)
#pragma unroll
      for (int j = 0; j < 4; ++j) sc[i][j] = (f32x4){0.f, 0.f, 0.f, 0.f};
#pragma unroll
    for (int kk = 0; kk < 2; ++kk) {
      bf16x8 kf[4];
#pragma unroll
      for (int j = 0; j < 4; ++j) {
        const int row = j * 16 + fr;
        kf[j] = *(const bf16x8*)&Ks[cur][row * 64 + ((kk * 32 + kg) ^ ((row & 7) << 3))];
      }
#pragma unroll
      for (int i = 0; i < 2; ++i)
#pragma unroll
        for (int j = 0; j < 4; ++j)
          sc[i][j] = __builtin_amdgcn_mfma_f32_16x16x32_bf16(qf[i][kk], kf[j], sc[i][j], 0, 0, 0);
    }

    // ---- online softmax, defer-max fast path (no shuffles) ----
    float pmx[2][4];
    int ok = 1;
#pragma unroll
    for (int i = 0; i < 2; ++i)
#pragma unroll
      for (int r = 0; r < 4; ++r) {
        const float m3 = fmaxf(fmaxf(sc[i][0][r], sc[i][1][r]),
                               fmaxf(sc[i][2][r], sc[i][3][r]));
        pmx[i][r] = m3;
        ok &= (m3 <= mrun[i][r] + 8.f) ? 1 : 0;
      }
    if (!__all(ok)) {   // slow path: full max reduce + rescale (rare)
#pragma unroll
      for (int i = 0; i < 2; ++i)
#pragma unroll
        for (int r = 0; r < 4; ++r) {
          float mx = pmx[i][r];
#pragma unroll
          for (int m = 1; m < 16; m <<= 1) mx = fmaxf(mx, __shfl_xor(mx, m));
          const float mnew = fmaxf(mrun[i][r], mx);
          const float alpha = exp2f(mrun[i][r] - mnew);
          mrun[i][r] = mnew;
          lrun[i][r] *= alpha;
#pragma unroll
          for (int j = 0; j < 4; ++j) octx[i][j][r] *= alpha;
        }
    }
#pragma unroll
    for (int i = 0; i < 2; ++i)
#pragma unroll
      for (int r = 0; r < 4; ++r) {
        const float m = mrun[i][r];
        float s = 0.f;
#pragma unroll
        for (int j = 0; j < 4; ++j) {
          const float p = exp2f(sc[i][j][r] - m);
          sc[i][j][r] = p;
          s += p;
        }
        lrun[i][r] += s;   // per-lane partial; reduced once at the end
        const int prow = wave * 32 + i * 16 + lr + r;
#pragma unroll
        for (int j = 0; j < 4; ++j)
          Ps[prow * 64 + (((j * 16 + lc)) ^ ((prow & 7) << 3))] = (bf16_t)sc[i][j][r];
      }
    asm volatile("s_waitcnt lgkmcnt(0)" ::: "memory");  // P writes -> own reads

    // ctx += P @ V   (Bt form: Vs[c][kv])
#pragma unroll
    for (int kk = 0; kk < 2; ++kk) {
      bf16x8 pf[2], vf[4];
#pragma unroll
      for (int i = 0; i < 2; ++i) {
        const int row = wave * 32 + i * 16 + fr;
        pf[i] = *(const bf16x8*)&Ps[row * 64 + ((kk * 32 + kg) ^ ((row & 7) << 3))];
      }
#pragma unroll
      for (int j = 0; j < 4; ++j) {
        const int row = j * 16 + fr;
        vf[j] = *(const bf16x8*)&Vs[cur][row * 64 + ((kk * 32 + kg) ^ ((row & 7) << 3))];
      }
#pragma unroll
      for (int i = 0; i < 2; ++i)
#pragma unroll
        for (int j = 0; j < 4; ++j)
          octx[i][j] = __builtin_amdgcn_mfma_f32_16x16x32_bf16(pf[i], vf[j], octx[i][j], 0, 0, 0);
    }

    // next tile staged AND everyone done reading cur before it's re-staged
    asm volatile("s_waitcnt vmcnt(0)" ::: "memory");
    __syncthreads();
  }

  // epilogue: single row-sum reduce, normalize, write ctx [token, h*64+c]
#pragma unroll
  for (int i = 0; i < 2; ++i)
#pragma unroll
    for (int r = 0; r < 4; ++r) {
      float l = lrun[i][r];
#pragma unroll
      for (int m = 1; m < 16; m <<= 1) l += __shfl_xor(l, m);
      const float inv = 1.f / l;
      const int row = qt + wave * 32 + i * 16 + lr + r;
#pragma unroll
      for (int j = 0; j < 4; ++j) {
        const int c = j * 16 + lc;
        CTX[((size_t)(b_ * SEQ + row)) * DMODEL + h_ * HD + c] = (bf16_t)(octx[i][j][r] * inv);
      }
    }
}

// ---------------------------------------------------------------------------
// residual + LayerNorm: out = LN(X+Y)*g + b ; optional bf16 copy
__global__ __launch_bounds__(256)
void ln_kernel(const float* __restrict__ X, const float* __restrict__ Y,
               const float* __restrict__ g, const float* __restrict__ b,
               float* __restrict__ outf, bf16_t* __restrict__ outb) {
  const int row = blockIdx.x, tid = threadIdx.x;
  const int wave = tid >> 6, lane = tid & 63;
  const float4 xv = ((const float4*)X)[(size_t)row * 256 + tid];
  const float4 yv = ((const float4*)Y)[(size_t)row * 256 + tid];
  const float s0 = xv.x + yv.x, s1 = xv.y + yv.y, s2 = xv.z + yv.z, s3 = xv.w + yv.w;
  float sum = s0 + s1 + s2 + s3;
  float sq = s0 * s0 + s1 * s1 + s2 * s2 + s3 * s3;
#pragma unroll
  for (int off = 1; off < 64; off <<= 1) {
    sum += __shfl_xor(sum, off);
    sq += __shfl_xor(sq, off);
  }
  __shared__ float red[8];
  if (lane == 0) { red[wave] = sum; red[4 + wave] = sq; }
  __syncthreads();
  sum = red[0] + red[1] + red[2] + red[3];
  sq = red[4] + red[5] + red[6] + red[7];
  const float mu = sum * (1.f / 1024.f);
  const float var = sq * (1.f / 1024.f) - mu * mu;
  const float rstd = rsqrtf(var + 1e-5f);
  const float4 gv = ((const float4*)g)[tid];
  const float4 bv = ((const float4*)b)[tid];
  const float o0 = (s0 - mu) * rstd * gv.x + bv.x;
  const float o1 = (s1 - mu) * rstd * gv.y + bv.y;
  const float o2 = (s2 - mu) * rstd * gv.z + bv.z;
  const float o3 = (s3 - mu) * rstd * gv.w + bv.w;
  ((float4*)outf)[(size_t)row * 256 + tid] = make_float4(o0, o1, o2, o3);
  if (outb) {
    bf16x4 ob = { (bf16_t)o0, (bf16_t)o1, (bf16_t)o2, (bf16_t)o3 };
    *(bf16x4*)&outb[(size_t)row * 1024 + tid * 4] = ob;
  }
}

// ---------------------------------------------------------------------------
extern "C" void kernel_launch(void* const* d_in, const int* in_sizes, int n_in,
                              void* d_out, int out_size, void* d_ws, size_t ws_size,
                              hipStream_t stream) {
  const float* x   = (const float*)d_in[0];
  const float* Wq  = (const float*)d_in[1];
  const float* bq  = (const float*)d_in[2];
  const float* Wk  = (const float*)d_in[3];
  const float* bk  = (const float*)d_in[4];
  const float* Wv  = (const float*)d_in[5];
  const float* bv  = (const float*)d_in[6];
  const float* Wo  = (const float*)d_in[7];
  const float* bo  = (const float*)d_in[8];
  const float* g1  = (const float*)d_in[9];
  const float* be1 = (const float*)d_in[10];
  const float* W1  = (const float*)d_in[11];
  const float* b1  = (const float*)d_in[12];
  const float* W2  = (const float*)d_in[13];
  const float* b2  = (const float*)d_in[14];
  const float* g2  = (const float*)d_in[15];
  const float* be2 = (const float*)d_in[16];

  char* ws = (char*)d_ws;
  size_t off = 0;
  auto alloc = [&](size_t bytes) {
    char* p = ws + off;
    off += (bytes + 255) & ~(size_t)255;
    return p;
  };
  const size_t MB = 1u << 20;
  bf16_t* xb  = (bf16_t*)alloc(16 * MB);  // x bf16; reused as CTX after QKV
  bf16_t* WqT = (bf16_t*)alloc(2 * MB);
  bf16_t* WkT = (bf16_t*)alloc(2 * MB);
  bf16_t* WvT = (bf16_t*)alloc(2 * MB);
  bf16_t* WoT = (bf16_t*)alloc(2 * MB);
  bf16_t* W1T = (bf16_t*)alloc(4 * MB);
  bf16_t* W2T = (bf16_t*)alloc(4 * MB);
  bf16_t* qb  = (bf16_t*)alloc(16 * MB);  // reused as hb after attention
  bf16_t* kb  = (bf16_t*)alloc(16 * MB);  // kb+vT reused as u (ffn1 out)
  bf16_t* vT  = (bf16_t*)alloc(16 * MB);
  float*  attnf = (float*)alloc(32 * MB); // reused as y (ffn2 out)
  float*  h     = (float*)alloc(32 * MB);
  bf16_t* ctx = xb;
  bf16_t* hb  = qb;
  bf16_t* u   = kb;
  float*  y   = attnf;

  // prep: casts + transposes
  cast_bf16_kernel<<<dim3(NTOK * DMODEL / 4 / 256), dim3(256), 0, stream>>>(x, xb, NTOK * DMODEL / 4);
  transpose_cast_kernel<<<dim3(32, 32), dim3(32, 8), 0, stream>>>(Wq, WqT, 1024, 1024);
  transpose_cast_kernel<<<dim3(32, 32), dim3(32, 8), 0, stream>>>(Wk, WkT, 1024, 1024);
  transpose_cast_kernel<<<dim3(32, 32), dim3(32, 8), 0, stream>>>(Wv, WvT, 1024, 1024);
  transpose_cast_kernel<<<dim3(32, 32), dim3(32, 8), 0, stream>>>(Wo, WoT, 1024, 1024);
  transpose_cast_kernel<<<dim3(64, 32), dim3(32, 8), 0, stream>>>(W1, W1T, 1024, 2048);
  transpose_cast_kernel<<<dim3(32, 64), dim3(32, 8), 0, stream>>>(W2, W2T, 2048, 1024);

  // QKV projections.  Q pre-scaled by 1/sqrt(64)*log2(e) for exp2-domain
  // softmax in the attention kernel.
  const float qscale = 0.125f * 1.44269504088896f;
  gemm_bt<2><<<dim3(64, 8), dim3(256), 0, stream>>>(xb, WqT, bq, qb, NTOK, DMODEL, DMODEL, qscale);
  gemm_bt<2><<<dim3(64, 8), dim3(256), 0, stream>>>(xb, WkT, bk, kb, NTOK, DMODEL, DMODEL, 1.0f);
  gemm_bt<3><<<dim3(64, 8), dim3(256), 0, stream>>>(xb, WvT, bv, vT, NTOK, DMODEL, DMODEL, 1.0f);

  // attention (writes ctx == xb; xb no longer needed)
  attn_kernel<<<dim3(128, 8), dim3(256), 0, stream>>>(qb, kb, vT, ctx);

  // output projection + residual + LN1
  gemm_bt<0><<<dim3(64, 8), dim3(256), 0, stream>>>(ctx, WoT, bo, attnf, NTOK, DMODEL, DMODEL, 1.0f);
  ln_kernel<<<dim3(NTOK), dim3(256), 0, stream>>>(x, attnf, g1, be1, h, hb);

  // FFN
  gemm_bt<1><<<dim3(64, 16), dim3(256), 0, stream>>>(hb, W1T, b1, u, NTOK, FFDIM, DMODEL, 1.0f);
  gemm_bt<0><<<dim3(64, 8), dim3(256), 0, stream>>>(u, W2T, b2, y, NTOK, DMODEL, FFDIM, 1.0f);
  ln_kernel<<<dim3(NTOK), dim3(256), 0, stream>>>(h, y, g2, be2, (float*)d_out, nullptr);
}